// Round 6
// baseline (303.797 us; speedup 1.0000x reference)
//
#include <hip/hip_runtime.h>

#define BB 32
#define NN 2048
#define DD 65
#define HH 64
#define ST 68                // padded leading dim (16B-aligned float4 frags)
#define TILE (DD * ST)       // 4420 floats per padded 65x65 matrix
#define NCH 16               // 128-row chunks per batch
#define GRID (BB * NCH)      // 512 blocks == 2/CU by LDS packing (70.2 KB/blk)
#define ROWS 128

__device__ __forceinline__ float4 f4add(float4 a, float4 b) {
  return make_float4(a.x + b.x, a.y + b.y, a.z + b.z, a.w + b.w);
}

__global__ void kinit(unsigned int* ctr) { *ctr = 0u; }

// Monotone-counter grid barrier: co-residency of all GRID blocks is
// guaranteed because LDS (70176 B) packs exactly 2 blocks/CU and
// GRID == 2 * 256 CUs. Counter zeroed by kinit each launch; targets are
// cumulative (GRID, 2*GRID) so no reset between barriers.
__device__ __forceinline__ void gridbar(unsigned int* ctr,
                                        unsigned int target) {
  __threadfence();
  __syncthreads();
  if (threadIdx.x == 0) {
    __hip_atomic_fetch_add(ctr, 1u, __ATOMIC_ACQ_REL,
                           __HIP_MEMORY_SCOPE_AGENT);
    while (__hip_atomic_load(ctr, __ATOMIC_ACQUIRE,
                             __HIP_MEMORY_SCOPE_AGENT) < target)
      __builtin_amdgcn_s_sleep(8);
  }
  __syncthreads();
}

// ---------------------------------------------------------------------------
// fused: phase1 partial Gram (512 blocks x 128 rows) -> P; barrier;
// phase2 (32 blocks) G = tree-reduce(P), M = Wq^T Wk, R = M G, T = R Wv^T
// -> Tm; barrier; phase3 out rows from the x tile STILL RESIDENT in LDS.
// ---------------------------------------------------------------------------
__global__ __launch_bounds__(256, 2) void fused(
    const float* __restrict__ x, const float* __restrict__ Wq,
    const float* __restrict__ Wk, const float* __restrict__ Wv,
    float* __restrict__ P, float* __restrict__ Tm, float* __restrict__ out,
    unsigned int* __restrict__ ctr) {
  __shared__ __align__(16) float Xl[ROWS * ST];   // 34816 B, lives all phases
  __shared__ __align__(16) float A[TILE];         // 17680 B
  __shared__ __align__(16) float Bf[TILE];        // 17680 B
  const int t = (int)threadIdx.x;
  const int tx = t & 15, ty = t >> 4;
  const int blk = (int)blockIdx.x;
  const int b = blk >> 4, c = blk & 15;

  // ---------------- phase 1: partial Gram over 128 rows ----------------
  {
    // 128*65 = 8320 floats = 2080 float4, base 16B-aligned. 9 loads in
    // flight per thread, scalar scatter into padded LDS.
    const float4* s4 =
        (const float4*)(x + ((size_t)b * NN + (size_t)c * ROWS) * DD);
    float4 tmp[9];
#pragma unroll
    for (int q = 0; q < 9; q++) {
      const int i4 = t + 256 * q;
      if (i4 < ROWS * DD / 4) tmp[q] = s4[i4];
    }
#pragma unroll
    for (int q = 0; q < 9; q++) {
      const int i4 = t + 256 * q;
      if (i4 < ROWS * DD / 4) {
        const int base = 4 * i4;
        const float v[4] = {tmp[q].x, tmp[q].y, tmp[q].z, tmp[q].w};
#pragma unroll
        for (int e = 0; e < 4; e++) {
          const int idx = base + e;
          const int r = idx / DD;
          Xl[r * ST + (idx - r * DD)] = v[e];
        }
      }
    }
  }
  __syncthreads();
  {
    float g[4][4] = {}, g64[4] = {}, gcc = 0.f;
    for (int n = 0; n < ROWS; n++) {
      float rowf[4], colf[4];
      *(float4*)rowf = *(const float4*)&Xl[n * ST + 4 * ty];
      *(float4*)colf = *(const float4*)&Xl[n * ST + 4 * tx];
#pragma unroll
      for (int r = 0; r < 4; r++)
#pragma unroll
        for (int cc = 0; cc < 4; cc++)
          g[r][cc] = fmaf(rowf[r], colf[cc], g[r][cc]);
      if (ty == 0) {
        const float x64 = Xl[n * ST + 64];
#pragma unroll
        for (int cc = 0; cc < 4; cc++) g64[cc] = fmaf(x64, colf[cc], g64[cc]);
        if (tx == 0) gcc = fmaf(x64, x64, gcc);
      }
    }
    float* Pp = P + (size_t)blk * TILE;
#pragma unroll
    for (int r = 0; r < 4; r++)
      *(float4*)&Pp[(4 * ty + r) * ST + 4 * tx] = *(float4*)g[r];
    if (ty == 0) {
      *(float4*)&Pp[64 * ST + 4 * tx] = *(float4*)g64;  // G[64][j]
#pragma unroll
      for (int cc = 0; cc < 4; cc++)
        Pp[(4 * tx + cc) * ST + 64] = g64[cc];          // symmetry
      if (tx == 0) Pp[64 * ST + 64] = gcc;
    }
  }
  gridbar(ctr, GRID);

  // ---------------- phase 2: 32 blocks run the 65x65 chain -------------
  if (blk < BB) {
    const int b2 = blk;
    // stage Wq -> A, Wk -> Bf (34 loads in flight)
    {
      float tq[17], tk[17];
#pragma unroll
      for (int q = 0; q < 17; q++) {
        const int idx = t + 256 * q;
        if (idx < HH * DD) { tq[q] = Wq[idx]; tk[q] = Wk[idx]; }
      }
#pragma unroll
      for (int q = 0; q < 17; q++) {
        const int idx = t + 256 * q;
        if (idx < HH * DD) {
          const int r = idx / DD, cc = idx - r * DD;
          A[r * ST + cc] = tq[q];
          Bf[r * ST + cc] = tk[q];
        }
      }
    }
    __syncthreads();
    // M = Wq^T Wk (regs)
    float m[4][4] = {}, mrow[4] = {}, mcol[4] = {}, mcc = 0.f;
    for (int h = 0; h < HH; h++) {
      float qa[4], kb[4];
      *(float4*)qa = *(const float4*)&A[h * ST + 4 * ty];
      *(float4*)kb = *(const float4*)&Bf[h * ST + 4 * tx];
#pragma unroll
      for (int r = 0; r < 4; r++)
#pragma unroll
        for (int cc = 0; cc < 4; cc++)
          m[r][cc] = fmaf(qa[r], kb[cc], m[r][cc]);
      if (ty == 0) {
        const float q64 = A[h * ST + 64];
#pragma unroll
        for (int cc = 0; cc < 4; cc++) mrow[cc] = fmaf(q64, kb[cc], mrow[cc]);
      }
      if (tx == 0) {
        const float k64 = Bf[h * ST + 64];
#pragma unroll
        for (int r = 0; r < 4; r++) mcol[r] = fmaf(qa[r], k64, mcol[r]);
        if (ty == 0) mcc = fmaf(A[h * ST + 64], k64, mcc);
      }
    }
    __syncthreads();
    // write M -> A; reduce P -> Bf (16-way float4 tree, 16 loads in flight)
#pragma unroll
    for (int r = 0; r < 4; r++)
      *(float4*)&A[(4 * ty + r) * ST + 4 * tx] = *(float4*)m[r];
    if (ty == 0) *(float4*)&A[64 * ST + 4 * tx] = *(float4*)mrow;
    if (tx == 0) {
#pragma unroll
      for (int r = 0; r < 4; r++) A[(4 * ty + r) * ST + 64] = mcol[r];
    }
    if (t == 0) A[64 * ST + 64] = mcc;
    {
      const float4* Pb = (const float4*)(P + (size_t)b2 * NCH * TILE);
      const int Q = TILE / 4;  // 1105
#pragma unroll
      for (int sq = 0; sq < 5; sq++) {
        const int i4 = t + 256 * sq;
        if (i4 < Q) {
          float4 v[NCH];
#pragma unroll
          for (int cc = 0; cc < NCH; cc++) v[cc] = Pb[(size_t)cc * Q + i4];
#pragma unroll
          for (int stp = NCH / 2; stp >= 1; stp >>= 1)
#pragma unroll
            for (int cc = 0; cc < stp; cc++) v[cc] = f4add(v[cc], v[cc + stp]);
          *((float4*)Bf + i4) = v[0];
        }
      }
    }
    __syncthreads();
    // R = M G (regs)
    float rr[4][4] = {}, r64j[4] = {}, ri64[4] = {}, rcc = 0.f;
    for (int k = 0; k < DD; k++) {
      float gb[4], ma[4];
      *(float4*)gb = *(const float4*)&Bf[k * ST + 4 * tx];
#pragma unroll
      for (int r = 0; r < 4; r++) ma[r] = A[(4 * ty + r) * ST + k];
#pragma unroll
      for (int r = 0; r < 4; r++)
#pragma unroll
        for (int cc = 0; cc < 4; cc++)
          rr[r][cc] = fmaf(ma[r], gb[cc], rr[r][cc]);
      if (ty == 0) {
        const float m64 = A[64 * ST + k];
#pragma unroll
        for (int cc = 0; cc < 4; cc++) r64j[cc] = fmaf(m64, gb[cc], r64j[cc]);
      }
      if (tx == 0) {
        const float g64 = Bf[k * ST + 64];
#pragma unroll
        for (int r = 0; r < 4; r++) ri64[r] = fmaf(ma[r], g64, ri64[r]);
        if (ty == 0) rcc = fmaf(A[64 * ST + k], g64, rcc);
      }
    }
    __syncthreads();
    // write R -> A; stage Wv^T -> Bf
#pragma unroll
    for (int r = 0; r < 4; r++)
      *(float4*)&A[(4 * ty + r) * ST + 4 * tx] = *(float4*)rr[r];
    if (ty == 0) *(float4*)&A[64 * ST + 4 * tx] = *(float4*)r64j;
    if (tx == 0) {
#pragma unroll
      for (int r = 0; r < 4; r++) A[(4 * ty + r) * ST + 64] = ri64[r];
    }
    if (t == 0) A[64 * ST + 64] = rcc;
    {
      float tv[17];
#pragma unroll
      for (int q = 0; q < 17; q++) {
        const int idx = t + 256 * q;
        if (idx < DD * DD) tv[q] = Wv[idx];
      }
#pragma unroll
      for (int q = 0; q < 17; q++) {
        const int idx = t + 256 * q;
        if (idx < DD * DD) {
          const int j = idx / DD, k = idx - j * DD;
          Bf[k * ST + j] = tv[q];
        }
      }
    }
    __syncthreads();
    // T = R Wv^T; write Tm[b2] row-major (T[k][j] at Tb[k*ST+j])
    float tt[4][4] = {}, row64[4] = {}, col64[4] = {}, tcc = 0.f;
    for (int k = 0; k < DD; k++) {
      float wv[4], ra[4];
      *(float4*)wv = *(const float4*)&Bf[k * ST + 4 * tx];
#pragma unroll
      for (int ir = 0; ir < 4; ir++) ra[ir] = A[(4 * ty + ir) * ST + k];
#pragma unroll
      for (int ir = 0; ir < 4; ir++)
#pragma unroll
        for (int jc = 0; jc < 4; jc++)
          tt[ir][jc] = fmaf(ra[ir], wv[jc], tt[ir][jc]);
      if (ty == 0) {
        const float r64 = A[64 * ST + k];
#pragma unroll
        for (int jc = 0; jc < 4; jc++)
          row64[jc] = fmaf(r64, wv[jc], row64[jc]);
      }
      if (tx == 0) {
        const float w64 = Bf[k * ST + 64];
#pragma unroll
        for (int ir = 0; ir < 4; ir++)
          col64[ir] = fmaf(ra[ir], w64, col64[ir]);
        if (ty == 0) tcc = fmaf(A[64 * ST + k], w64, tcc);
      }
    }
    float* Tb = Tm + (size_t)b2 * TILE;
#pragma unroll
    for (int ir = 0; ir < 4; ir++)
      *(float4*)&Tb[(4 * ty + ir) * ST + 4 * tx] = *(float4*)tt[ir];
    if (ty == 0) *(float4*)&Tb[64 * ST + 4 * tx] = *(float4*)row64;
    if (tx == 0) {
#pragma unroll
      for (int ir = 0; ir < 4; ir++)
        Tb[(4 * ty + ir) * ST + 64] = col64[ir];
    }
    if (t == 0) Tb[64 * ST + 64] = tcc;
  }
  gridbar(ctr, 2 * GRID);

  // ---------------- phase 3: out = Xl @ T[b], Xl still resident --------
  {
    const float4* Tg4 = (const float4*)(Tm + (size_t)b * TILE);
    float4 tT[5];
#pragma unroll
    for (int q = 0; q < 5; q++) {
      const int i4 = t + 256 * q;
      if (i4 < TILE / 4) tT[q] = Tg4[i4];
    }
#pragma unroll
    for (int q = 0; q < 5; q++) {
      const int i4 = t + 256 * q;
      if (i4 < TILE / 4) *((float4*)A + i4) = tT[q];
    }
  }
  __syncthreads();
  const size_t rowbase = (size_t)b * NN + (size_t)c * ROWS;
  for (int h = 0; h < 2; h++) {   // two 64-row halves: 2-way LDS alias only
    float o[4][4] = {}, o64[4] = {};
    for (int k = 0; k < DD; k++) {
      float xa[4], tb[4];
#pragma unroll
      for (int r = 0; r < 4; r++)
        xa[r] = Xl[(64 * h + 4 * ty + r) * ST + k];
      *(float4*)tb = *(const float4*)&A[k * ST + 4 * tx];
#pragma unroll
      for (int r = 0; r < 4; r++)
#pragma unroll
        for (int cc = 0; cc < 4; cc++)
          o[r][cc] = fmaf(xa[r], tb[cc], o[r][cc]);
      if (tx == 0) {
        const float t64 = A[k * ST + 64];
#pragma unroll
        for (int r = 0; r < 4; r++) o64[r] = fmaf(xa[r], t64, o64[r]);
      }
    }
    float* ob = out + (rowbase + 64 * h) * DD;
#pragma unroll
    for (int r = 0; r < 4; r++)
#pragma unroll
      for (int cc = 0; cc < 4; cc++)
        ob[(4 * ty + r) * DD + 4 * tx + cc] = o[r][cc];
    if (tx == 0) {
#pragma unroll
      for (int r = 0; r < 4; r++) ob[(4 * ty + r) * DD + 64] = o64[r];
    }
  }
}

extern "C" void kernel_launch(void* const* d_in, const int* in_sizes, int n_in,
                              void* d_out, int out_size, void* d_ws,
                              size_t ws_size, hipStream_t stream) {
  const float* x = (const float*)d_in[0];
  const float* Wq = (const float*)d_in[1];
  const float* Wk = (const float*)d_in[2];
  const float* Wv = (const float*)d_in[3];
  float* out = (float*)d_out;

  // ws: P[512 tiles] (9.05 MB) + Tm[32 tiles] (0.57 MB) + barrier counter.
  float* P = (float*)d_ws;
  float* Tm = P + (size_t)GRID * TILE;
  unsigned int* ctr = (unsigned int*)(Tm + (size_t)BB * TILE);

  kinit<<<1, 1, 0, stream>>>(ctr);
  fused<<<GRID, 256, 0, stream>>>(x, Wq, Wk, Wv, P, Tm, out, ctr);
  (void)in_sizes; (void)n_in; (void)out_size; (void)ws_size;
}

// Round 7
// 148.225 us; speedup vs baseline: 2.0496x; 2.0496x over previous
//
#include <hip/hip_runtime.h>

#define BB 32
#define NN 2048
#define DD 65
#define HH 64
#define ST 68                // padded leading dim (16B-aligned float4 frags)
#define TILE (DD * ST)       // 4420 floats per padded 65x65 matrix
#define NCH 16               // 128-row chunks per batch
#define ROWS 128

__device__ __forceinline__ float4 f4add(float4 a, float4 b) {
  return make_float4(a.x + b.x, a.y + b.y, a.z + b.z, a.w + b.w);
}

// ---------------------------------------------------------------------------
// k1: partial Gram P[b][c] = (128-row x chunk)^T (chunk), 65x65 stride-68.
// 512 blocks (2/CU by LDS at 34.8KB -> actually 4/CU possible; TLP hides LDS
// latency). 16x16 threads, 4x4 regs over 64x64 core; ty==0 patches edge 64.
// ---------------------------------------------------------------------------
__global__ __launch_bounds__(256) void k1_gram(const float* __restrict__ x,
                                               float* __restrict__ P) {
  __shared__ __align__(16) float Xl[ROWS * ST];
  const int t = (int)threadIdx.x;
  const int tx = t & 15, ty = t >> 4;
  const int blk = (int)blockIdx.x;
  const int b = blk >> 4, c = blk & 15;

  {  // stage 128x65 rows: float4 batched (9 in flight), scalar scatter
    const float4* s4 =
        (const float4*)(x + ((size_t)b * NN + (size_t)c * ROWS) * DD);
    float4 tmp[9];
#pragma unroll
    for (int q = 0; q < 9; q++) {
      const int i4 = t + 256 * q;
      if (i4 < ROWS * DD / 4) tmp[q] = s4[i4];
    }
#pragma unroll
    for (int q = 0; q < 9; q++) {
      const int i4 = t + 256 * q;
      if (i4 < ROWS * DD / 4) {
        const int base = 4 * i4;
        const float v[4] = {tmp[q].x, tmp[q].y, tmp[q].z, tmp[q].w};
#pragma unroll
        for (int e = 0; e < 4; e++) {
          const int idx = base + e;
          const int r = idx / DD;
          Xl[r * ST + (idx - r * DD)] = v[e];
        }
      }
    }
  }
  __syncthreads();

  float g[4][4] = {}, g64[4] = {}, gcc = 0.f;
  for (int n = 0; n < ROWS; n++) {
    float rowf[4], colf[4];
    *(float4*)rowf = *(const float4*)&Xl[n * ST + 4 * ty];
    *(float4*)colf = *(const float4*)&Xl[n * ST + 4 * tx];
#pragma unroll
    for (int r = 0; r < 4; r++)
#pragma unroll
      for (int cc = 0; cc < 4; cc++)
        g[r][cc] = fmaf(rowf[r], colf[cc], g[r][cc]);
    if (ty == 0) {
      const float x64 = Xl[n * ST + 64];
#pragma unroll
      for (int cc = 0; cc < 4; cc++) g64[cc] = fmaf(x64, colf[cc], g64[cc]);
      if (tx == 0) gcc = fmaf(x64, x64, gcc);
    }
  }
  float* Pp = P + (size_t)blk * TILE;
#pragma unroll
  for (int r = 0; r < 4; r++)
    *(float4*)&Pp[(4 * ty + r) * ST + 4 * tx] = *(float4*)g[r];
  if (ty == 0) {
    *(float4*)&Pp[64 * ST + 4 * tx] = *(float4*)g64;  // G[64][j]
#pragma unroll
    for (int cc = 0; cc < 4; cc++)
      Pp[(4 * tx + cc) * ST + 64] = g64[cc];          // G[i][64] by symmetry
    if (tx == 0) Pp[64 * ST + 64] = gcc;
  }
}

// ---------------------------------------------------------------------------
// k2: per batch: G = 16-way float4 tree-reduce(P); M = Wq^T Wk; R = M G;
// T = R Wv^T -> Tm row-major. 16x16 threads / 4x4 regs; edge patches for 64.
// ---------------------------------------------------------------------------
__global__ __launch_bounds__(256) void k2_chain(
    const float* __restrict__ Wq, const float* __restrict__ Wk,
    const float* __restrict__ Wv, const float* __restrict__ P,
    float* __restrict__ Tm) {
  __shared__ __align__(16) float A[TILE];
  __shared__ __align__(16) float Bf[TILE];
  const int t = (int)threadIdx.x;
  const int tx = t & 15, ty = t >> 4;
  const int b = (int)blockIdx.x;

  // phase 0: stage Wq -> A, Wk -> Bf (34 loads in flight)
  {
    float tq[17], tk[17];
#pragma unroll
    for (int q = 0; q < 17; q++) {
      const int idx = t + 256 * q;
      if (idx < HH * DD) { tq[q] = Wq[idx]; tk[q] = Wk[idx]; }
    }
#pragma unroll
    for (int q = 0; q < 17; q++) {
      const int idx = t + 256 * q;
      if (idx < HH * DD) {
        const int r = idx / DD, cc = idx - r * DD;
        A[r * ST + cc] = tq[q];
        Bf[r * ST + cc] = tk[q];
      }
    }
  }
  __syncthreads();

  // phase 1: M = Wq^T Wk (regs)
  float m[4][4] = {}, mrow[4] = {}, mcol[4] = {}, mcc = 0.f;
  for (int h = 0; h < HH; h++) {
    float qa[4], kb[4];
    *(float4*)qa = *(const float4*)&A[h * ST + 4 * ty];
    *(float4*)kb = *(const float4*)&Bf[h * ST + 4 * tx];
#pragma unroll
    for (int r = 0; r < 4; r++)
#pragma unroll
      for (int cc = 0; cc < 4; cc++) m[r][cc] = fmaf(qa[r], kb[cc], m[r][cc]);
    if (ty == 0) {
      const float q64 = A[h * ST + 64];
#pragma unroll
      for (int cc = 0; cc < 4; cc++) mrow[cc] = fmaf(q64, kb[cc], mrow[cc]);
    }
    if (tx == 0) {
      const float k64 = Bf[h * ST + 64];
#pragma unroll
      for (int r = 0; r < 4; r++) mcol[r] = fmaf(qa[r], k64, mcol[r]);
      if (ty == 0) mcc = fmaf(A[h * ST + 64], k64, mcc);
    }
  }
  __syncthreads();

  // phase 2: write M -> A; reduce P -> Bf (16 float4 loads in flight + tree)
#pragma unroll
  for (int r = 0; r < 4; r++)
    *(float4*)&A[(4 * ty + r) * ST + 4 * tx] = *(float4*)m[r];
  if (ty == 0) *(float4*)&A[64 * ST + 4 * tx] = *(float4*)mrow;
  if (tx == 0) {
#pragma unroll
    for (int r = 0; r < 4; r++) A[(4 * ty + r) * ST + 64] = mcol[r];
  }
  if (t == 0) A[64 * ST + 64] = mcc;
  {
    const float4* Pb = (const float4*)(P + (size_t)b * NCH * TILE);
    const int Q = TILE / 4;  // 1105
#pragma unroll
    for (int sq = 0; sq < 5; sq++) {
      const int i4 = t + 256 * sq;
      if (i4 < Q) {
        float4 v[NCH];
#pragma unroll
        for (int cc = 0; cc < NCH; cc++) v[cc] = Pb[(size_t)cc * Q + i4];
#pragma unroll
        for (int stp = NCH / 2; stp >= 1; stp >>= 1)
#pragma unroll
          for (int cc = 0; cc < stp; cc++) v[cc] = f4add(v[cc], v[cc + stp]);
        *((float4*)Bf + i4) = v[0];
      }
    }
  }
  __syncthreads();

  // phase 3: R = M G (regs)
  float rr[4][4] = {}, r64j[4] = {}, ri64[4] = {}, rcc = 0.f;
  for (int k = 0; k < DD; k++) {
    float gb[4], ma[4];
    *(float4*)gb = *(const float4*)&Bf[k * ST + 4 * tx];
#pragma unroll
    for (int r = 0; r < 4; r++) ma[r] = A[(4 * ty + r) * ST + k];
#pragma unroll
    for (int r = 0; r < 4; r++)
#pragma unroll
      for (int cc = 0; cc < 4; cc++)
        rr[r][cc] = fmaf(ma[r], gb[cc], rr[r][cc]);
    if (ty == 0) {
      const float m64 = A[64 * ST + k];
#pragma unroll
      for (int cc = 0; cc < 4; cc++) r64j[cc] = fmaf(m64, gb[cc], r64j[cc]);
    }
    if (tx == 0) {
      const float g64 = Bf[k * ST + 64];
#pragma unroll
      for (int r = 0; r < 4; r++) ri64[r] = fmaf(ma[r], g64, ri64[r]);
      if (ty == 0) rcc = fmaf(A[64 * ST + k], g64, rcc);
    }
  }
  __syncthreads();

  // phase 4: write R -> A; stage Wv^T -> Bf
#pragma unroll
  for (int r = 0; r < 4; r++)
    *(float4*)&A[(4 * ty + r) * ST + 4 * tx] = *(float4*)rr[r];
  if (ty == 0) *(float4*)&A[64 * ST + 4 * tx] = *(float4*)r64j;
  if (tx == 0) {
#pragma unroll
    for (int r = 0; r < 4; r++) A[(4 * ty + r) * ST + 64] = ri64[r];
  }
  if (t == 0) A[64 * ST + 64] = rcc;
  {
    float tv[17];
#pragma unroll
    for (int q = 0; q < 17; q++) {
      const int idx = t + 256 * q;
      if (idx < DD * DD) tv[q] = Wv[idx];
    }
#pragma unroll
    for (int q = 0; q < 17; q++) {
      const int idx = t + 256 * q;
      if (idx < DD * DD) {
        const int j = idx / DD, k = idx - j * DD;
        Bf[k * ST + j] = tv[q];
      }
    }
  }
  __syncthreads();

  // phase 5: T = R Wv^T
  float tt[4][4] = {}, row64[4] = {}, col64[4] = {}, tcc = 0.f;
  for (int k = 0; k < DD; k++) {
    float wv[4], ra[4];
    *(float4*)wv = *(const float4*)&Bf[k * ST + 4 * tx];
#pragma unroll
    for (int ir = 0; ir < 4; ir++) ra[ir] = A[(4 * ty + ir) * ST + k];
#pragma unroll
    for (int ir = 0; ir < 4; ir++)
#pragma unroll
      for (int jc = 0; jc < 4; jc++)
        tt[ir][jc] = fmaf(ra[ir], wv[jc], tt[ir][jc]);
    if (ty == 0) {
      const float r64 = A[64 * ST + k];
#pragma unroll
      for (int jc = 0; jc < 4; jc++) row64[jc] = fmaf(r64, wv[jc], row64[jc]);
    }
    if (tx == 0) {
      const float w64 = Bf[k * ST + 64];
#pragma unroll
      for (int ir = 0; ir < 4; ir++) col64[ir] = fmaf(ra[ir], w64, col64[ir]);
      if (ty == 0) tcc = fmaf(A[64 * ST + k], w64, tcc);
    }
  }
  float* Tb = Tm + (size_t)b * TILE;
#pragma unroll
  for (int ir = 0; ir < 4; ir++)
    *(float4*)&Tb[(4 * ty + ir) * ST + 4 * tx] = *(float4*)tt[ir];
  if (ty == 0) *(float4*)&Tb[64 * ST + 4 * tx] = *(float4*)row64;  // T[64][j]
  if (tx == 0) {
#pragma unroll
    for (int ir = 0; ir < 4; ir++)
      Tb[(4 * ty + ir) * ST + 64] = col64[ir];                     // T[i][64]
  }
  if (t == 0) Tb[64 * ST + 64] = tcc;
}

// ---------------------------------------------------------------------------
// k3: out[b] = x[b] @ T[b]. 64 rows per block (1024 blocks, 4/CU); T staged
// as pure float4 copy, x batched; 4x4 reg tiling; tx==0 patches column 64.
// ---------------------------------------------------------------------------
__global__ __launch_bounds__(256) void k3_out(const float* __restrict__ x,
                                              const float* __restrict__ Tt,
                                              float* __restrict__ out) {
  __shared__ __align__(16) float Tl[TILE];
  __shared__ __align__(16) float Xl[64 * ST];
  const int t = (int)threadIdx.x;
  const int tx = t & 15, ty = t >> 4;
  const int blk = (int)blockIdx.x;
  const int b = blk >> 5;           // 32 blocks per batch
  const int rb = (blk & 31) * 64;
  const float4* Tg4 = (const float4*)(Tt + (size_t)b * TILE);
  const float* src = x + ((size_t)b * NN + rb) * DD;
  {
    float4 tT[5];
    float tX[17];
#pragma unroll
    for (int q = 0; q < 5; q++) {
      const int i4 = t + 256 * q;
      if (i4 < TILE / 4) tT[q] = Tg4[i4];
    }
#pragma unroll
    for (int q = 0; q < 17; q++) {
      const int idx = t + 256 * q;
      if (idx < 64 * DD) tX[q] = src[idx];
    }
#pragma unroll
    for (int q = 0; q < 5; q++) {
      const int i4 = t + 256 * q;
      if (i4 < TILE / 4) *((float4*)Tl + i4) = tT[q];
    }
#pragma unroll
    for (int q = 0; q < 17; q++) {
      const int idx = t + 256 * q;
      if (idx < 64 * DD) {
        const int r = idx / DD;
        Xl[r * ST + (idx - r * DD)] = tX[q];
      }
    }
  }
  __syncthreads();

  float o[4][4] = {}, o64[4] = {};
  for (int k = 0; k < DD; k++) {
    float xa[4], tb[4];
#pragma unroll
    for (int r = 0; r < 4; r++) xa[r] = Xl[(4 * ty + r) * ST + k];
    *(float4*)tb = *(const float4*)&Tl[k * ST + 4 * tx];
#pragma unroll
    for (int r = 0; r < 4; r++)
#pragma unroll
      for (int cc = 0; cc < 4; cc++) o[r][cc] = fmaf(xa[r], tb[cc], o[r][cc]);
    if (tx == 0) {
      const float t64 = Tl[k * ST + 64];
#pragma unroll
      for (int r = 0; r < 4; r++) o64[r] = fmaf(xa[r], t64, o64[r]);
    }
  }
  float* ob = out + ((size_t)b * NN + rb) * DD;
#pragma unroll
  for (int r = 0; r < 4; r++)
#pragma unroll
    for (int cc = 0; cc < 4; cc++)
      ob[(4 * ty + r) * DD + 4 * tx + cc] = o[r][cc];
  if (tx == 0) {
#pragma unroll
    for (int r = 0; r < 4; r++) ob[(4 * ty + r) * DD + 64] = o64[r];
  }
}

extern "C" void kernel_launch(void* const* d_in, const int* in_sizes, int n_in,
                              void* d_out, int out_size, void* d_ws,
                              size_t ws_size, hipStream_t stream) {
  const float* x = (const float*)d_in[0];
  const float* Wq = (const float*)d_in[1];
  const float* Wk = (const float*)d_in[2];
  const float* Wv = (const float*)d_in[3];
  float* out = (float*)d_out;

  // ws: P[512 tiles] (9.05 MB) + Tm[32 tiles] (0.57 MB).
  float* P = (float*)d_ws;
  float* Tm = P + (size_t)BB * NCH * TILE;

  k1_gram<<<BB * NCH, 256, 0, stream>>>(x, P);
  k2_chain<<<BB, 256, 0, stream>>>(Wq, Wk, Wv, P, Tm);
  k3_out<<<BB * 32, 256, 0, stream>>>(x, Tm, out);
  (void)in_sizes; (void)n_in; (void)out_size; (void)ws_size;
}